// Round 9
// baseline (292.815 us; speedup 1.0000x reference)
//
#include <hip/hip_runtime.h>

typedef _Float16 f16;
typedef __attribute__((ext_vector_type(4))) _Float16 f16x4;
typedef __attribute__((ext_vector_type(8))) _Float16 f16x8;
typedef __attribute__((ext_vector_type(4))) float f32x4;

#define BATCH 8
#define NTOK 1025
#define DIM 768
#define HEADS 12
#define HD 64
#define MTOT (BATCH * NTOK)      // 8200
#define MPAD 8320                // 65*128
#define NQP2 1152                // q rows padded to 9*128
#define NKP 1088                 // kv rows padded to 17*64
#define NQPO 1056                // po/pl q stride (33*32, >= NTOK)
#define NUMREL 3972

// Explicit DMA drain before barrier: correctness REQUIRES vmcnt(0)
// between global_load_lds issue and s_barrier (prior-session divergence).
#define DMA_FENCE asm volatile("s_waitcnt vmcnt(0)" ::: "memory")

__device__ __forceinline__ int imin(int a, int b) { return a < b ? a : b; }

__device__ __forceinline__ void gl_lds16(const f16* g, f16* l) {
  __builtin_amdgcn_global_load_lds(
      (const __attribute__((address_space(1))) unsigned int*)g,
      (__attribute__((address_space(3))) unsigned int*)l, 16, 0, 0);
}

// ---------------------------------------------------------------------------
// Kernel C: f32 -> f16 cast, 3 arrays in one launch
// ---------------------------------------------------------------------------
__global__ __launch_bounds__(256) void cast3(const float* __restrict__ s0,
                                             f16* __restrict__ d0, int n0,
                                             const float* __restrict__ s1,
                                             f16* __restrict__ d1, int n1,
                                             const float* __restrict__ s2,
                                             f16* __restrict__ d2, int n2) {
  const float* s = (blockIdx.y == 0) ? s0 : (blockIdx.y == 1) ? s1 : s2;
  f16* d = (blockIdx.y == 0) ? d0 : (blockIdx.y == 1) ? d1 : d2;
  int n = (blockIdx.y == 0) ? n0 : (blockIdx.y == 1) ? n1 : n2;
  for (size_t i = ((size_t)blockIdx.x * 256 + threadIdx.x) * 8; i < (size_t)n;
       i += (size_t)gridDim.x * 256 * 8) {
    float4 a = *(const float4*)(s + i);
    float4 b = *(const float4*)(s + i + 4);
    f16x8 r;
    r[0] = (f16)a.x; r[1] = (f16)a.y; r[2] = (f16)a.z; r[3] = (f16)a.w;
    r[4] = (f16)b.x; r[5] = (f16)b.y; r[6] = (f16)b.z; r[7] = (f16)b.w;
    *(f16x8*)(d + i) = r;
  }
}

// ---------------------------------------------------------------------------
// Kernel 0: bias table in TRANSPOSED-S fragment order (coalesced f16x8
// loads in attn -- the R7/R8 lesson: per-lane L1 gathers serialize; the
// materialized table reads 2 cache lines/wave instead of 64):
//   tbl[h][kt][q 0..1087][lg 0..3][c*4+r] = bias(q, kv=kt*64+c*16+lg*4+r)
// ---------------------------------------------------------------------------
__device__ __forceinline__ float rpb_bias(const float* __restrict__ rpb, int qg,
                                          int kg, int h) {
  int idx;
  if (kg == 0) {
    idx = (qg == 0) ? (NUMREL - 1) : (NUMREL - 2);
  } else if (qg == 0) {
    idx = NUMREL - 3;
  } else {
    int qq = imin(qg, 1024) - 1, kk = imin(kg, 1024) - 1;
    int di = (qq >> 5) - (kk >> 5);
    int dj = (qq & 31) - (kk & 31);
    idx = (di + 31) * 63 + (dj + 31);
  }
  return rpb[idx * HEADS + h];
}

__global__ __launch_bounds__(256) void bias_pre(const float* __restrict__ rpb,
                                                f16* __restrict__ tbl) {
  const int kt = blockIdx.x / 17;
  const int qb17 = blockIdx.x % 17;
  const int h = blockIdx.y;
  const int tid = threadIdx.x;
  const int q = qb17 * 64 + (tid >> 2);
  const int lg = tid & 3;
  f16 vals[16];
#pragma unroll
  for (int c = 0; c < 4; c++)
#pragma unroll
    for (int r = 0; r < 4; r++) {
      int kv = kt * 64 + c * 16 + lg * 4 + r;
      float v = (kv >= NTOK) ? -30000.f : rpb_bias(rpb, q, kv, h);
      vals[c * 4 + r] = (f16)v;
    }
  size_t off = ((((size_t)h * 17 + kt) * NKP + q) * 4 + lg) * 16;
  *(f16x8*)(tbl + off) = *(const f16x8*)(&vals[0]);
  *(f16x8*)(tbl + off + 8) = *(const f16x8*)(&vals[8]);
}

// ---------------------------------------------------------------------------
// Kernel 1: qkv = xh @ wh^T + [q_bias,0,v_bias]; split Q(scaled)/K/V^T.
// BM=128 x BN=256, 512 threads / 8 waves (wave tile 64x64, acc[4][4]),
// BK=64 SINGLE-buffered drain staging. GRID (9,65): tN fast.
// ---------------------------------------------------------------------------
__global__ __launch_bounds__(512) void qkv_gemm(
    const f16* __restrict__ Ah, const f16* __restrict__ Bh,
    const float* __restrict__ q_bias, const float* __restrict__ v_bias,
    f16* __restrict__ qb, f16* __restrict__ kb, f16* __restrict__ vtb) {
  __shared__ f16 As[128][64];  // 16 KB
  __shared__ f16 Bs[256][64];  // 32 KB
  const int tid = threadIdx.x;
  const int lane = tid & 63, w = tid >> 6;   // w: 0..7
  const int wm = w >> 2, wn = w & 3;         // 2 M-halves x 4 N-quarters
  const int lr = lane & 15, lg = lane >> 4;
  const int tN = blockIdx.x;  // 0..8  (fast dim: A-tile sharers adjacent)
  const int tM = blockIdx.y;  // 0..64
  const int r8 = lane >> 3;             // 0..7 (row within 8-row DMA slab)
  const int swch = (lane & 7) ^ r8;     // 8-chunk XOR swizzle (global side)
  const int lr7 = lr & 7;

  const f16* Ab = Ah + ((size_t)tM * 128 + r8) * DIM + swch * 8;
  const f16* Bb = Bh + ((size_t)tN * 256 + r8) * DIM + swch * 8;

  f32x4 acc[4][4] = {};

  for (int kt = 0; kt < 12; kt++) {
    // A: 128 rows over 8 waves -> 2 slabs/wave; B: 256 rows -> 4 slabs/wave.
#pragma unroll
    for (int pp = 0; pp < 2; pp++) {
      int rowb = w * 16 + pp * 8;
      gl_lds16(Ab + (size_t)rowb * DIM + kt * 64, &As[rowb][0]);
    }
#pragma unroll
    for (int pp = 0; pp < 4; pp++) {
      int rowb = w * 32 + pp * 8;
      gl_lds16(Bb + (size_t)rowb * DIM + kt * 64, &Bs[rowb][0]);
    }
    DMA_FENCE;        // own DMA (tile kt) complete before barrier
    __syncthreads();  // all waves' DMA complete -> tile kt readable
#pragma unroll
    for (int ks = 0; ks < 2; ks++) {
      f16x8 af[4], bf[4];
      int rc = ((ks * 4 + lg) ^ lr7) * 8;
#pragma unroll
      for (int i = 0; i < 4; i++) {
        af[i] = *(const f16x8*)(&As[wm * 64 + i * 16 + lr][rc]);
        bf[i] = *(const f16x8*)(&Bs[wn * 64 + i * 16 + lr][rc]);
      }
#pragma unroll
      for (int mi = 0; mi < 4; mi++)
#pragma unroll
        for (int ni = 0; ni < 4; ni++)
          acc[mi][ni] = __builtin_amdgcn_mfma_f32_16x16x32_f16(
              af[mi], bf[ni], acc[mi][ni], 0, 0, 0);
    }
    __syncthreads();  // all reads done before next tile's DMA overwrites
  }

  const int which = tN / 3;   // 0:Q 1:K 2:V (256-col block never crosses)
  const int nb = tN % 3;
#pragma unroll
  for (int mi = 0; mi < 4; mi++) {
#pragma unroll
    for (int ni = 0; ni < 4; ni++) {
      int ncol = nb * 256 + wn * 64 + ni * 16 + lr;  // 0..767
      int h = ncol >> 6, dd = ncol & 63;
      float bias = 0.f;
      if (which == 0) bias = q_bias[ncol];
      if (which == 2) bias = v_bias[ncol];
#pragma unroll
      for (int r = 0; r < 4; r++) {
        int m = tM * 128 + wm * 64 + mi * 16 + lg * 4 + r;
        if (m >= MTOT) continue;
        int b = m / NTOK;
        int t = m - b * NTOK;
        int bh = b * HEADS + h;
        float v = acc[mi][ni][r] + bias;
        if (which == 0)
          qb[((size_t)bh * NQP2 + t) * HD + dd] = (f16)(v * 0.125f);
        else if (which == 1)
          kb[((size_t)bh * NKP + t) * HD + dd] = (f16)v;
        else
          vtb[((size_t)bh * HD + dd) * NKP + t] = (f16)v;
      }
    }
  }
}

// ---------------------------------------------------------------------------
// Kernel 2: fused flash attention, R6 structure + KV-SPLIT=2.
// Grid 960 = 8b * 5qpair * 12h * 2half (b fastest) -> ~3 blocks/CU resident
// (vs 1.875 at grid 480): raises subscription of every pipe at once — the
// diagnosis after R7/R8 falsified the byte-bound model (attn is latency-
// bound; nothing saturated at 480 blocks). half0: kt 0..8, half1: kt 9..16.
// No running max in this softmax -> partials combine exactly:
//   po[half] = unnormalized O (f32), pl[half] = row sums; out = Σpo / Σpl.
// Plds inner dim 72 -> 68: measured 8-way read bank conflict -> ~4-way.
// ---------------------------------------------------------------------------
__global__ __launch_bounds__(512) void attn_kernel(
    const f16* __restrict__ qb, const f16* __restrict__ kb,
    const f16* __restrict__ vtb, const f16* __restrict__ tbl,
    float* __restrict__ po, float* __restrict__ pl) {
  __shared__ f16 Ks[2][64][64];   // 16 KB
  __shared__ f16 Vs[2][64][64];   // 16 KB
  __shared__ f16 Plds[8][16][68]; // 17 KB
  const int tid = threadIdx.x;
  const int lane = tid & 63, w = tid >> 6;  // w: 0..7
  const int lr = lane & 15, lg = lane >> 4;
  const int b = blockIdx.x & 7;          // fastest: bias-slab sharers adjacent
  const int rest = blockIdx.x >> 3;      // 0..119
  const int qpair = rest % 5;            // 0..4
  const int hh = rest / 5;               // 0..23
  const int h = hh % 12;
  const int half = hh / 12;              // 0..1
  const int kt0 = half ? 9 : 0;
  const int kt1 = half ? 17 : 9;
  const int qblk = qpair * 2 + (w >> 2); // 0..9 (9 = masked pad)
  const int bh = b * HEADS + h;
  const int q0 = qblk * 128 + (w & 3) * 32;

  const f16* kbase = kb + (size_t)bh * NKP * HD;
  const f16* vbase = vtb + (size_t)bh * HD * NKP;

  const int srow8 = lane >> 3;
  const int swch = (lane & 7) ^ srow8;

  // Prologue: stage tile kt0 (64 K rows + 64 V rows over 8 waves).
  {
    int row = w * 8 + srow8;
    gl_lds16(kbase + (size_t)(kt0 * 64 + row) * HD + swch * 8,
             &Ks[kt0 & 1][w * 8][0]);
    gl_lds16(vbase + (size_t)row * NKP + kt0 * 64 + swch * 8,
             &Vs[kt0 & 1][w * 8][0]);
  }

  f16x8 aq[2][2];
#pragma unroll
  for (int g = 0; g < 2; g++) {
    const f16* qp = qb + ((size_t)bh * NQP2 + q0 + g * 16 + lr) * HD + lg * 8;
    aq[g][0] = *(const f16x8*)(qp);
    aq[g][1] = *(const f16x8*)(qp + 32);
  }

  const size_t ktstride = (size_t)NKP * 64;
  const f16* bp[2];
#pragma unroll
  for (int g = 0; g < 2; g++) {
    int qt = imin(q0 + g * 16 + lr, NKP - 1);
    bp[g] = tbl + (((size_t)h * 17 * NKP + qt) * 4 + lg) * 16;
  }
  f16x8 bb[2][2];
#pragma unroll
  for (int g = 0; g < 2; g++) {
    const f16* p8 = bp[g] + (size_t)kt0 * ktstride;
    bb[g][0] = *(const f16x8*)(p8);
    bb[g][1] = *(const f16x8*)(p8 + 8);
  }

  float lsum[2] = {0.f, 0.f};
  f32x4 oacc[2][4] = {};
  const int sw8 = lr & 7;

  for (int kt = kt0; kt < kt1; kt++) {
    const int bi = kt & 1;
    DMA_FENCE;        // own DMA (tile kt) complete before barrier
    __syncthreads();
    if (kt + 1 < kt1) {
      int row = w * 8 + srow8;
      gl_lds16(kbase + (size_t)((kt + 1) * 64 + row) * HD + swch * 8,
               &Ks[bi ^ 1][w * 8][0]);
      gl_lds16(vbase + (size_t)row * NKP + (kt + 1) * 64 + swch * 8,
               &Vs[bi ^ 1][w * 8][0]);
    }
    f16x8 nb[2][2] = {};
    if (kt + 1 < kt1) {
#pragma unroll
      for (int g = 0; g < 2; g++) {
        const f16* p8 = bp[g] + (size_t)(kt + 1) * ktstride;
        nb[g][0] = *(const f16x8*)(p8);
        nb[g][1] = *(const f16x8*)(p8 + 8);
      }
    }
    f32x4 s[2][4];
#pragma unroll
    for (int g = 0; g < 2; g++)
#pragma unroll
      for (int c = 0; c < 4; c++) {
        const f16* src = (const f16*)&bb[g][c >> 1];
#pragma unroll
        for (int r = 0; r < 4; r++) s[g][c][r] = (float)src[(c & 1) * 4 + r];
      }
#pragma unroll
    for (int c = 0; c < 4; c++) {
      f16x8 kf0 = *(const f16x8*)(&Ks[bi][c * 16 + lr][(lg ^ sw8) * 8]);
      f16x8 kf1 = *(const f16x8*)(&Ks[bi][c * 16 + lr][((lg + 4) ^ sw8) * 8]);
      s[0][c] = __builtin_amdgcn_mfma_f32_16x16x32_f16(kf0, aq[0][0], s[0][c], 0, 0, 0);
      s[0][c] = __builtin_amdgcn_mfma_f32_16x16x32_f16(kf1, aq[0][1], s[0][c], 0, 0, 0);
      s[1][c] = __builtin_amdgcn_mfma_f32_16x16x32_f16(kf0, aq[1][0], s[1][c], 0, 0, 0);
      s[1][c] = __builtin_amdgcn_mfma_f32_16x16x32_f16(kf1, aq[1][1], s[1][c], 0, 0, 0);
    }
#pragma unroll
    for (int g = 0; g < 2; g++)
#pragma unroll
      for (int c = 0; c < 4; c++)
#pragma unroll
        for (int r = 0; r < 4; r++) {
          float p = __expf(s[g][c][r]);
          s[g][c][r] = p;
          lsum[g] += p;
        }
    f16x8 ap[2][2];
#pragma unroll
    for (int g = 0; g < 2; g++) {
#pragma unroll
      for (int c = 0; c < 4; c++) {
        f16x4 pk;
        pk[0] = (f16)s[g][c][0];
        pk[1] = (f16)s[g][c][1];
        pk[2] = (f16)s[g][c][2];
        pk[3] = (f16)s[g][c][3];
        *(f16x4*)(&Plds[w][lr][c * 16 + lg * 4]) = pk;
      }
      ap[g][0] = *(const f16x8*)(&Plds[w][lr][lg * 8]);
      ap[g][1] = *(const f16x8*)(&Plds[w][lr][32 + lg * 8]);
    }
#pragma unroll
    for (int dblk = 0; dblk < 4; dblk++) {
      f16x8 vf0 = *(const f16x8*)(&Vs[bi][dblk * 16 + lr][(lg ^ sw8) * 8]);
      f16x8 vf1 = *(const f16x8*)(&Vs[bi][dblk * 16 + lr][((lg + 4) ^ sw8) * 8]);
      oacc[0][dblk] = __builtin_amdgcn_mfma_f32_16x16x32_f16(ap[0][0], vf0, oacc[0][dblk], 0, 0, 0);
      oacc[0][dblk] = __builtin_amdgcn_mfma_f32_16x16x32_f16(ap[0][1], vf1, oacc[0][dblk], 0, 0, 0);
      oacc[1][dblk] = __builtin_amdgcn_mfma_f32_16x16x32_f16(ap[1][0], vf0, oacc[1][dblk], 0, 0, 0);
      oacc[1][dblk] = __builtin_amdgcn_mfma_f32_16x16x32_f16(ap[1][1], vf1, oacc[1][dblk], 0, 0, 0);
    }
#pragma unroll
    for (int g = 0; g < 2; g++) {
      bb[g][0] = nb[g][0];
      bb[g][1] = nb[g][1];
    }
  }
  // Partial store: unnormalized O (f32) + row sums. Combine kernel divides.
  float* pob = po + ((size_t)half * 96 + bh) * NQPO * 64;
  float* plb = pl + ((size_t)half * 96 + bh) * NQPO;
#pragma unroll
  for (int g = 0; g < 2; g++) {
    float ls = lsum[g];
    ls += __shfl_xor(ls, 16);
    ls += __shfl_xor(ls, 32);
    int qrow = q0 + g * 16 + lr;
    if (lg == 0 && qrow < NTOK) plb[qrow] = ls;
#pragma unroll
    for (int dblk = 0; dblk < 4; dblk++)
#pragma unroll
      for (int r = 0; r < 4; r++) {
        int qg = q0 + g * 16 + lg * 4 + r;
        if (qg >= NTOK) continue;
        pob[(size_t)qg * 64 + dblk * 16 + lr] = oacc[g][dblk][r];
      }
  }
}

// ---------------------------------------------------------------------------
// Kernel 2b: combine halves: ob = (po0 + po1) / (pl0 + pl1), f16.
// One thread per 8 d-elems; fully coalesced. 3075 blocks x 256.
// ---------------------------------------------------------------------------
__global__ __launch_bounds__(256) void combine(const float* __restrict__ po,
                                               const float* __restrict__ pl,
                                               f16* __restrict__ ob) {
  size_t i = (size_t)blockIdx.x * 256 + threadIdx.x;
  const size_t TOT = (size_t)BATCH * NTOK * HEADS * 8;
  if (i >= TOT) return;
  int d8 = (int)(i & 7);
  size_t t = i >> 3;
  int h = (int)(t % HEADS);
  size_t bq = t / HEADS;                 // 0..8199
  int b = (int)(bq / NTOK);
  int q = (int)(bq - (size_t)b * NTOK);
  int bh = b * HEADS + h;
  size_t r0 = ((size_t)bh * NQPO + q) * 64 + d8 * 8;
  size_t r1 = ((size_t)(96 + bh) * NQPO + q) * 64 + d8 * 8;
  float inv = 1.f / (pl[(size_t)bh * NQPO + q] + pl[(size_t)(96 + bh) * NQPO + q]);
  float4 a0 = *(const float4*)(po + r0);
  float4 a1 = *(const float4*)(po + r0 + 4);
  float4 b0 = *(const float4*)(po + r1);
  float4 b1 = *(const float4*)(po + r1 + 4);
  f16x8 r;
  r[0] = (f16)((a0.x + b0.x) * inv);
  r[1] = (f16)((a0.y + b0.y) * inv);
  r[2] = (f16)((a0.z + b0.z) * inv);
  r[3] = (f16)((a0.w + b0.w) * inv);
  r[4] = (f16)((a1.x + b1.x) * inv);
  r[5] = (f16)((a1.y + b1.y) * inv);
  r[6] = (f16)((a1.z + b1.z) * inv);
  r[7] = (f16)((a1.w + b1.w) * inv);
  *(f16x8*)(ob + bq * DIM + h * HD + d8 * 8) = r;
}

// ---------------------------------------------------------------------------
// Kernel 3: out = ob @ pwh^T + proj_b. BM=128 x BN=256, 512 threads / 8
// waves (wave 64x64), BK=64 single-buffered. GRID (3,65): tN fast.
// ---------------------------------------------------------------------------
__global__ __launch_bounds__(512) void proj_gemm(const f16* __restrict__ Ah,
                                                 const f16* __restrict__ Bh,
                                                 const float* __restrict__ pb,
                                                 float* __restrict__ out) {
  __shared__ f16 As[128][64];
  __shared__ f16 Bs[256][64];
  const int tid = threadIdx.x;
  const int lane = tid & 63, w = tid >> 6;
  const int wm = w >> 2, wn = w & 3;
  const int lr = lane & 15, lg = lane >> 4;
  const int tN = blockIdx.x;  // 0..2  (fast dim)
  const int tM = blockIdx.y;  // 0..64
  const int r8 = lane >> 3;
  const int swch = (lane & 7) ^ r8;
  const int lr7 = lr & 7;

  const f16* Ab = Ah + ((size_t)tM * 128 + r8) * DIM + swch * 8;
  const f16* Bb = Bh + ((size_t)tN * 256 + r8) * DIM + swch * 8;

  f32x4 acc[4][4] = {};

  for (int kt = 0; kt < 12; kt++) {
#pragma unroll
    for (int pp = 0; pp < 2; pp++) {
      int rowb = w * 16 + pp * 8;
      gl_lds16(Ab + (size_t)rowb * DIM + kt * 64, &As[rowb][0]);
    }
#pragma unroll
    for (int pp = 0; pp < 4; pp++) {
      int rowb = w * 32 + pp * 8;
      gl_lds16(Bb + (size_t)rowb * DIM + kt * 64, &Bs[rowb][0]);
    }
    DMA_FENCE;
    __syncthreads();
#pragma unroll
    for (int ks = 0; ks < 2; ks++) {
      f16x8 af[4], bf[4];
      int rc = ((ks * 4 + lg) ^ lr7) * 8;
#pragma unroll
      for (int i = 0; i < 4; i++) {
        af[i] = *(const f16x8*)(&As[wm * 64 + i * 16 + lr][rc]);
        bf[i] = *(const f16x8*)(&Bs[wn * 64 + i * 16 + lr][rc]);
      }
#pragma unroll
      for (int mi = 0; mi < 4; mi++)
#pragma unroll
        for (int ni = 0; ni < 4; ni++)
          acc[mi][ni] = __builtin_amdgcn_mfma_f32_16x16x32_f16(
              af[mi], bf[ni], acc[mi][ni], 0, 0, 0);
    }
    __syncthreads();
  }

#pragma unroll
  for (int mi = 0; mi < 4; mi++) {
#pragma unroll
    for (int ni = 0; ni < 4; ni++) {
      int n = tN * 256 + wn * 64 + ni * 16 + lr;
      float bias = pb[n];
#pragma unroll
      for (int r = 0; r < 4; r++) {
        int m = tM * 128 + wm * 64 + mi * 16 + lg * 4 + r;
        if (m >= MTOT) continue;
        out[(size_t)m * DIM + n] = acc[mi][ni][r] + bias;
      }
    }
  }
}

extern "C" void kernel_launch(void* const* d_in, const int* in_sizes, int n_in,
                              void* d_out, int out_size, void* d_ws,
                              size_t ws_size, hipStream_t stream) {
  const float* x = (const float*)d_in[0];
  const float* qkv_w = (const float*)d_in[1];
  const float* q_bias = (const float*)d_in[2];
  const float* v_bias = (const float*)d_in[3];
  const float* rpb = (const float*)d_in[4];
  const float* proj_w = (const float*)d_in[5];
  const float* proj_b = (const float*)d_in[6];
  float* out = (float*)d_out;

  f16* xh = (f16*)d_ws;                        // [MPAD,768]
  f16* wh = xh + (size_t)MPAD * DIM;           // [2304,768]
  f16* pwh = wh + (size_t)3 * DIM * DIM;       // [768,768]
  f16* qb = pwh + (size_t)DIM * DIM;           // [96,1152,64]
  f16* kb = qb + (size_t)BATCH * HEADS * NQP2 * HD;
  f16* vtb = kb + (size_t)BATCH * HEADS * NKP * HD;
  f16* ob = vtb + (size_t)BATCH * HEADS * NKP * HD;  // [MPAD,768]
  f16* tbl = ob + (size_t)MPAD * DIM;          // [12,17,1088,4,16]
  float* po = (float*)(tbl + (size_t)HEADS * 17 * NKP * 64);  // [2,96,1056,64]
  float* pl = po + (size_t)2 * 96 * NQPO * 64;                // [2,96,1056]

  cast3<<<dim3(1024, 3), 256, 0, stream>>>(
      x, xh, MTOT * DIM, qkv_w, wh, 3 * DIM * DIM, proj_w, pwh, DIM * DIM);
  bias_pre<<<dim3(17 * 17, HEADS), 256, 0, stream>>>(rpb, tbl);
  qkv_gemm<<<dim3(9, 65), 512, 0, stream>>>(xh, wh, q_bias, v_bias, qb, kb,
                                            vtb);
  attn_kernel<<<dim3(960), 512, 0, stream>>>(qb, kb, vtb, tbl, po, pl);
  combine<<<dim3(3075), 256, 0, stream>>>(po, pl, ob);
  proj_gemm<<<dim3(3, 65), 512, 0, stream>>>(ob, pwh, proj_b, out);
}

// Round 10
// 265.226 us; speedup vs baseline: 1.1040x; 1.1040x over previous
//
#include <hip/hip_runtime.h>

typedef _Float16 f16;
typedef __attribute__((ext_vector_type(4))) _Float16 f16x4;
typedef __attribute__((ext_vector_type(8))) _Float16 f16x8;
typedef __attribute__((ext_vector_type(4))) float f32x4;

#define BATCH 8
#define NTOK 1025
#define DIM 768
#define HEADS 12
#define HD 64
#define MTOT (BATCH * NTOK)      // 8200
#define MPAD 8320                // 65*128
#define NQP2 1152                // q rows padded to 9*128
#define NKP 1088                 // kv rows padded to 17*64
#define NUMREL 3972

// Explicit DMA drain before barrier: correctness REQUIRES vmcnt(0)
// between global_load_lds issue and s_barrier (prior-session divergence).
#define DMA_FENCE asm volatile("s_waitcnt vmcnt(0)" ::: "memory")

__device__ __forceinline__ int imin(int a, int b) { return a < b ? a : b; }

__device__ __forceinline__ void gl_lds16(const f16* g, f16* l) {
  __builtin_amdgcn_global_load_lds(
      (const __attribute__((address_space(1))) unsigned int*)g,
      (__attribute__((address_space(3))) unsigned int*)l, 16, 0, 0);
}

// ---------------------------------------------------------------------------
// Kernel P: fused prep. Blocks 0..3071: f32->f16 cast of {x, qkv_w, proj_w}
// (grid-stride, 1024 blocks each). Blocks 3072..6539: bias table build.
// The two jobs are independent; one launch overlaps their BW + saves a gap.
//   tbl[h][kt][q 0..1087][lg 0..3][c*4+r] = bias(q, kv=kt*64+c*16+lg*4+r)
// (R7/R8 lesson: attn must read bias as coalesced f16x8 vector loads — the
// materialized table touches 2 cache lines/wave vs 64 for per-lane gathers.)
// ---------------------------------------------------------------------------
__device__ __forceinline__ float rpb_bias(const float* __restrict__ rpb, int qg,
                                          int kg, int h) {
  int idx;
  if (kg == 0) {
    idx = (qg == 0) ? (NUMREL - 1) : (NUMREL - 2);
  } else if (qg == 0) {
    idx = NUMREL - 3;
  } else {
    int qq = imin(qg, 1024) - 1, kk = imin(kg, 1024) - 1;
    int di = (qq >> 5) - (kk >> 5);
    int dj = (qq & 31) - (kk & 31);
    idx = (di + 31) * 63 + (dj + 31);
  }
  return rpb[idx * HEADS + h];
}

__global__ __launch_bounds__(256) void prep(const float* __restrict__ s0,
                                            f16* __restrict__ d0, int n0,
                                            const float* __restrict__ s1,
                                            f16* __restrict__ d1, int n1,
                                            const float* __restrict__ s2,
                                            f16* __restrict__ d2, int n2,
                                            const float* __restrict__ rpb,
                                            f16* __restrict__ tbl) {
  const int bid = blockIdx.x;
  if (bid < 3072) {
    const int y = bid >> 10;             // 0..2
    const int bx = bid & 1023;
    const float* s = (y == 0) ? s0 : (y == 1) ? s1 : s2;
    f16* d = (y == 0) ? d0 : (y == 1) ? d1 : d2;
    int n = (y == 0) ? n0 : (y == 1) ? n1 : n2;
    for (size_t i = ((size_t)bx * 256 + threadIdx.x) * 8; i < (size_t)n;
         i += (size_t)1024 * 256 * 8) {
      float4 a = *(const float4*)(s + i);
      float4 b = *(const float4*)(s + i + 4);
      f16x8 r;
      r[0] = (f16)a.x; r[1] = (f16)a.y; r[2] = (f16)a.z; r[3] = (f16)a.w;
      r[4] = (f16)b.x; r[5] = (f16)b.y; r[6] = (f16)b.z; r[7] = (f16)b.w;
      *(f16x8*)(d + i) = r;
    }
    return;
  }
  // Bias-table part: linear block id -> (h, kt, qb17).
  const int bb = bid - 3072;             // 0..3467
  const int h = bb / 289;                // 0..11
  const int rem = bb - h * 289;          // 0..288
  const int kt = rem / 17;
  const int qb17 = rem - kt * 17;
  const int tid = threadIdx.x;
  const int q = qb17 * 64 + (tid >> 2);
  const int lg = tid & 3;
  f16 vals[16];
#pragma unroll
  for (int c = 0; c < 4; c++)
#pragma unroll
    for (int r = 0; r < 4; r++) {
      int kv = kt * 64 + c * 16 + lg * 4 + r;
      float v = (kv >= NTOK) ? -30000.f : rpb_bias(rpb, q, kv, h);
      vals[c * 4 + r] = (f16)v;
    }
  size_t off = ((((size_t)h * 17 + kt) * NKP + q) * 4 + lg) * 16;
  *(f16x8*)(tbl + off) = *(const f16x8*)(&vals[0]);
  *(f16x8*)(tbl + off + 8) = *(const f16x8*)(&vals[8]);
}

// ---------------------------------------------------------------------------
// Kernel 1: qkv = xh @ wh^T + [q_bias,0,v_bias]; split Q(scaled)/K/V^T.
// BM=128 x BN=256, 512 threads / 8 waves (wave tile 64x64, acc[4][4]),
// BK=64 SINGLE-buffered drain staging. GRID (9,65): tN fast.
// ---------------------------------------------------------------------------
__global__ __launch_bounds__(512) void qkv_gemm(
    const f16* __restrict__ Ah, const f16* __restrict__ Bh,
    const float* __restrict__ q_bias, const float* __restrict__ v_bias,
    f16* __restrict__ qb, f16* __restrict__ kb, f16* __restrict__ vtb) {
  __shared__ f16 As[128][64];  // 16 KB
  __shared__ f16 Bs[256][64];  // 32 KB
  const int tid = threadIdx.x;
  const int lane = tid & 63, w = tid >> 6;   // w: 0..7
  const int wm = w >> 2, wn = w & 3;         // 2 M-halves x 4 N-quarters
  const int lr = lane & 15, lg = lane >> 4;
  const int tN = blockIdx.x;  // 0..8  (fast dim: A-tile sharers adjacent)
  const int tM = blockIdx.y;  // 0..64
  const int r8 = lane >> 3;             // 0..7 (row within 8-row DMA slab)
  const int swch = (lane & 7) ^ r8;     // 8-chunk XOR swizzle (global side)
  const int lr7 = lr & 7;

  const f16* Ab = Ah + ((size_t)tM * 128 + r8) * DIM + swch * 8;
  const f16* Bb = Bh + ((size_t)tN * 256 + r8) * DIM + swch * 8;

  f32x4 acc[4][4] = {};

  for (int kt = 0; kt < 12; kt++) {
    // A: 128 rows over 8 waves -> 2 slabs/wave; B: 256 rows -> 4 slabs/wave.
#pragma unroll
    for (int pp = 0; pp < 2; pp++) {
      int rowb = w * 16 + pp * 8;
      gl_lds16(Ab + (size_t)rowb * DIM + kt * 64, &As[rowb][0]);
    }
#pragma unroll
    for (int pp = 0; pp < 4; pp++) {
      int rowb = w * 32 + pp * 8;
      gl_lds16(Bb + (size_t)rowb * DIM + kt * 64, &Bs[rowb][0]);
    }
    DMA_FENCE;        // own DMA (tile kt) complete before barrier
    __syncthreads();  // all waves' DMA complete -> tile kt readable
#pragma unroll
    for (int ks = 0; ks < 2; ks++) {
      f16x8 af[4], bf[4];
      int rc = ((ks * 4 + lg) ^ lr7) * 8;
#pragma unroll
      for (int i = 0; i < 4; i++) {
        af[i] = *(const f16x8*)(&As[wm * 64 + i * 16 + lr][rc]);
        bf[i] = *(const f16x8*)(&Bs[wn * 64 + i * 16 + lr][rc]);
      }
#pragma unroll
      for (int mi = 0; mi < 4; mi++)
#pragma unroll
        for (int ni = 0; ni < 4; ni++)
          acc[mi][ni] = __builtin_amdgcn_mfma_f32_16x16x32_f16(
              af[mi], bf[ni], acc[mi][ni], 0, 0, 0);
    }
    __syncthreads();  // all reads done before next tile's DMA overwrites
  }

  const int which = tN / 3;   // 0:Q 1:K 2:V (256-col block never crosses)
  const int nb = tN % 3;
#pragma unroll
  for (int mi = 0; mi < 4; mi++) {
#pragma unroll
    for (int ni = 0; ni < 4; ni++) {
      int ncol = nb * 256 + wn * 64 + ni * 16 + lr;  // 0..767
      int h = ncol >> 6, dd = ncol & 63;
      float bias = 0.f;
      if (which == 0) bias = q_bias[ncol];
      if (which == 2) bias = v_bias[ncol];
#pragma unroll
      for (int r = 0; r < 4; r++) {
        int m = tM * 128 + wm * 64 + mi * 16 + lg * 4 + r;
        if (m >= MTOT) continue;
        int b = m / NTOK;
        int t = m - b * NTOK;
        int bh = b * HEADS + h;
        float v = acc[mi][ni][r] + bias;
        if (which == 0)
          qb[((size_t)bh * NQP2 + t) * HD + dd] = (f16)(v * 0.125f);
        else if (which == 1)
          kb[((size_t)bh * NKP + t) * HD + dd] = (f16)v;
        else
          vtb[((size_t)bh * HD + dd) * NKP + t] = (f16)v;
      }
    }
  }
}

// ---------------------------------------------------------------------------
// Kernel 2: fused flash attention — R6 structure (best measured: 82 µs) with
// the R9-validated conflict-free Plds (inner dim 72 -> 68 drove
// SQ_LDS_BANK_CONFLICT 3.13M -> 0). 512 threads / 8 waves; waves 0-3 handle
// qblk 2j, waves 4-7 qblk 2j+1 (K/V staged once per 256 q rows). Grid 480 =
// 8b * 5qpair * 12h; qblk 9 masked by the qg<NTOK store guard.
// ---------------------------------------------------------------------------
__global__ __launch_bounds__(512) void attn_kernel(
    const f16* __restrict__ qb, const f16* __restrict__ kb,
    const f16* __restrict__ vtb, const f16* __restrict__ tbl,
    f16* __restrict__ ob) {
  __shared__ f16 Ks[2][64][64];   // 16 KB
  __shared__ f16 Vs[2][64][64];   // 16 KB
  __shared__ f16 Plds[8][16][68]; // 17 KB (68: conflict-free, measured R9)
  const int tid = threadIdx.x;
  const int lane = tid & 63, w = tid >> 6;  // w: 0..7
  const int lr = lane & 15, lg = lane >> 4;
  const int b = blockIdx.x & 7;          // fastest: bias-slab sharers adjacent
  const int t5 = blockIdx.x >> 3;        // 0..59
  const int qpair = t5 % 5;              // 0..4
  const int h = t5 / 5;                  // 0..11
  const int qblk = qpair * 2 + (w >> 2); // 0..9 (9 = masked pad)
  const int bh = b * HEADS + h;
  const int q0 = qblk * 128 + (w & 3) * 32;

  const f16* kbase = kb + (size_t)bh * NKP * HD;
  const f16* vbase = vtb + (size_t)bh * HD * NKP;

  const int srow8 = lane >> 3;
  const int swch = (lane & 7) ^ srow8;

  // Prologue: 64 K rows + 64 V rows over 8 waves -> 1 slab each per wave.
  {
    int row = w * 8 + srow8;
    gl_lds16(kbase + (size_t)row * HD + swch * 8, &Ks[0][w * 8][0]);
    gl_lds16(vbase + (size_t)row * NKP + swch * 8, &Vs[0][w * 8][0]);
  }

  f16x8 aq[2][2];
#pragma unroll
  for (int g = 0; g < 2; g++) {
    const f16* qp = qb + ((size_t)bh * NQP2 + q0 + g * 16 + lr) * HD + lg * 8;
    aq[g][0] = *(const f16x8*)(qp);
    aq[g][1] = *(const f16x8*)(qp + 32);
  }

  const f16* bp[2];
#pragma unroll
  for (int g = 0; g < 2; g++) {
    int qt = imin(q0 + g * 16 + lr, NKP - 1);
    bp[g] = tbl + (((size_t)h * 17 * NKP + qt) * 4 + lg) * 16;
  }
  f16x8 bb[2][2];
#pragma unroll
  for (int g = 0; g < 2; g++) {
    bb[g][0] = *(const f16x8*)(bp[g]);
    bb[g][1] = *(const f16x8*)(bp[g] + 8);
  }

  float lsum[2] = {0.f, 0.f};
  f32x4 oacc[2][4] = {};
  const int sw8 = lr & 7;
  const size_t ktstride = (size_t)NKP * 64;

  for (int kt = 0; kt < 17; kt++) {
    const int bi = kt & 1;
    DMA_FENCE;        // own DMA (tile kt) complete before barrier
    __syncthreads();
    if (kt + 1 < 17) {
      int row = w * 8 + srow8;
      gl_lds16(kbase + (size_t)((kt + 1) * 64 + row) * HD + swch * 8,
               &Ks[bi ^ 1][w * 8][0]);
      gl_lds16(vbase + (size_t)row * NKP + (kt + 1) * 64 + swch * 8,
               &Vs[bi ^ 1][w * 8][0]);
    }
    f16x8 nb[2][2] = {};
    if (kt + 1 < 17) {
#pragma unroll
      for (int g = 0; g < 2; g++) {
        const f16* p8 = bp[g] + (size_t)(kt + 1) * ktstride;
        nb[g][0] = *(const f16x8*)(p8);
        nb[g][1] = *(const f16x8*)(p8 + 8);
      }
    }
    f32x4 s[2][4];
#pragma unroll
    for (int g = 0; g < 2; g++)
#pragma unroll
      for (int c = 0; c < 4; c++) {
        const f16* src = (const f16*)&bb[g][c >> 1];
#pragma unroll
        for (int r = 0; r < 4; r++) s[g][c][r] = (float)src[(c & 1) * 4 + r];
      }
#pragma unroll
    for (int c = 0; c < 4; c++) {
      f16x8 kf0 = *(const f16x8*)(&Ks[bi][c * 16 + lr][(lg ^ sw8) * 8]);
      f16x8 kf1 = *(const f16x8*)(&Ks[bi][c * 16 + lr][((lg + 4) ^ sw8) * 8]);
      s[0][c] = __builtin_amdgcn_mfma_f32_16x16x32_f16(kf0, aq[0][0], s[0][c], 0, 0, 0);
      s[0][c] = __builtin_amdgcn_mfma_f32_16x16x32_f16(kf1, aq[0][1], s[0][c], 0, 0, 0);
      s[1][c] = __builtin_amdgcn_mfma_f32_16x16x32_f16(kf0, aq[1][0], s[1][c], 0, 0, 0);
      s[1][c] = __builtin_amdgcn_mfma_f32_16x16x32_f16(kf1, aq[1][1], s[1][c], 0, 0, 0);
    }
#pragma unroll
    for (int g = 0; g < 2; g++)
#pragma unroll
      for (int c = 0; c < 4; c++)
#pragma unroll
        for (int r = 0; r < 4; r++) {
          float p = __expf(s[g][c][r]);
          s[g][c][r] = p;
          lsum[g] += p;
        }
    f16x8 ap[2][2];
#pragma unroll
    for (int g = 0; g < 2; g++) {
#pragma unroll
      for (int c = 0; c < 4; c++) {
        f16x4 pk;
        pk[0] = (f16)s[g][c][0];
        pk[1] = (f16)s[g][c][1];
        pk[2] = (f16)s[g][c][2];
        pk[3] = (f16)s[g][c][3];
        *(f16x4*)(&Plds[w][lr][c * 16 + lg * 4]) = pk;
      }
      ap[g][0] = *(const f16x8*)(&Plds[w][lr][lg * 8]);
      ap[g][1] = *(const f16x8*)(&Plds[w][lr][32 + lg * 8]);
    }
#pragma unroll
    for (int dblk = 0; dblk < 4; dblk++) {
      f16x8 vf0 = *(const f16x8*)(&Vs[bi][dblk * 16 + lr][(lg ^ sw8) * 8]);
      f16x8 vf1 = *(const f16x8*)(&Vs[bi][dblk * 16 + lr][((lg + 4) ^ sw8) * 8]);
      oacc[0][dblk] = __builtin_amdgcn_mfma_f32_16x16x32_f16(ap[0][0], vf0, oacc[0][dblk], 0, 0, 0);
      oacc[0][dblk] = __builtin_amdgcn_mfma_f32_16x16x32_f16(ap[0][1], vf1, oacc[0][dblk], 0, 0, 0);
      oacc[1][dblk] = __builtin_amdgcn_mfma_f32_16x16x32_f16(ap[1][0], vf0, oacc[1][dblk], 0, 0, 0);
      oacc[1][dblk] = __builtin_amdgcn_mfma_f32_16x16x32_f16(ap[1][1], vf1, oacc[1][dblk], 0, 0, 0);
    }
#pragma unroll
    for (int g = 0; g < 2; g++) {
      bb[g][0] = nb[g][0];
      bb[g][1] = nb[g][1];
    }
  }
#pragma unroll
  for (int g = 0; g < 2; g++) {
    float ls = lsum[g];
    ls += __shfl_xor(ls, 16);
    ls += __shfl_xor(ls, 32);
    float inv[4];
#pragma unroll
    for (int r = 0; r < 4; r++) inv[r] = 1.f / __shfl(ls, lg * 4 + r);
#pragma unroll
    for (int dblk = 0; dblk < 4; dblk++)
#pragma unroll
      for (int r = 0; r < 4; r++) {
        int qg = q0 + g * 16 + lg * 4 + r;
        if (qg >= NTOK) continue;
        float v = oacc[g][dblk][r] * inv[r];
        ob[((size_t)(b * NTOK + qg)) * DIM + h * HD + dblk * 16 + lr] = (f16)v;
      }
  }
}

// ---------------------------------------------------------------------------
// Kernel 3: out = ob @ pwh^T + proj_b. BM=128 x BN=256, 512 threads / 8
// waves (wave 64x64), BK=64 single-buffered. GRID (3,65): tN fast.
// ---------------------------------------------------------------------------
__global__ __launch_bounds__(512) void proj_gemm(const f16* __restrict__ Ah,
                                                 const f16* __restrict__ Bh,
                                                 const float* __restrict__ pb,
                                                 float* __restrict__ out) {
  __shared__ f16 As[128][64];
  __shared__ f16 Bs[256][64];
  const int tid = threadIdx.x;
  const int lane = tid & 63, w = tid >> 6;
  const int wm = w >> 2, wn = w & 3;
  const int lr = lane & 15, lg = lane >> 4;
  const int tN = blockIdx.x;  // 0..2  (fast dim)
  const int tM = blockIdx.y;  // 0..64
  const int r8 = lane >> 3;
  const int swch = (lane & 7) ^ r8;
  const int lr7 = lr & 7;

  const f16* Ab = Ah + ((size_t)tM * 128 + r8) * DIM + swch * 8;
  const f16* Bb = Bh + ((size_t)tN * 256 + r8) * DIM + swch * 8;

  f32x4 acc[4][4] = {};

  for (int kt = 0; kt < 12; kt++) {
#pragma unroll
    for (int pp = 0; pp < 2; pp++) {
      int rowb = w * 16 + pp * 8;
      gl_lds16(Ab + (size_t)rowb * DIM + kt * 64, &As[rowb][0]);
    }
#pragma unroll
    for (int pp = 0; pp < 4; pp++) {
      int rowb = w * 32 + pp * 8;
      gl_lds16(Bb + (size_t)rowb * DIM + kt * 64, &Bs[rowb][0]);
    }
    DMA_FENCE;
    __syncthreads();
#pragma unroll
    for (int ks = 0; ks < 2; ks++) {
      f16x8 af[4], bf[4];
      int rc = ((ks * 4 + lg) ^ lr7) * 8;
#pragma unroll
      for (int i = 0; i < 4; i++) {
        af[i] = *(const f16x8*)(&As[wm * 64 + i * 16 + lr][rc]);
        bf[i] = *(const f16x8*)(&Bs[wn * 64 + i * 16 + lr][rc]);
      }
#pragma unroll
      for (int mi = 0; mi < 4; mi++)
#pragma unroll
        for (int ni = 0; ni < 4; ni++)
          acc[mi][ni] = __builtin_amdgcn_mfma_f32_16x16x32_f16(
              af[mi], bf[ni], acc[mi][ni], 0, 0, 0);
    }
    __syncthreads();
  }

#pragma unroll
  for (int mi = 0; mi < 4; mi++) {
#pragma unroll
    for (int ni = 0; ni < 4; ni++) {
      int n = tN * 256 + wn * 64 + ni * 16 + lr;
      float bias = pb[n];
#pragma unroll
      for (int r = 0; r < 4; r++) {
        int m = tM * 128 + wm * 64 + mi * 16 + lg * 4 + r;
        if (m >= MTOT) continue;
        out[(size_t)m * DIM + n] = acc[mi][ni][r] + bias;
      }
    }
  }
}

extern "C" void kernel_launch(void* const* d_in, const int* in_sizes, int n_in,
                              void* d_out, int out_size, void* d_ws,
                              size_t ws_size, hipStream_t stream) {
  const float* x = (const float*)d_in[0];
  const float* qkv_w = (const float*)d_in[1];
  const float* q_bias = (const float*)d_in[2];
  const float* v_bias = (const float*)d_in[3];
  const float* rpb = (const float*)d_in[4];
  const float* proj_w = (const float*)d_in[5];
  const float* proj_b = (const float*)d_in[6];
  float* out = (float*)d_out;

  f16* xh = (f16*)d_ws;                        // [MPAD,768]
  f16* wh = xh + (size_t)MPAD * DIM;           // [2304,768]
  f16* pwh = wh + (size_t)3 * DIM * DIM;       // [768,768]
  f16* qb = pwh + (size_t)DIM * DIM;           // [96,1152,64]
  f16* kb = qb + (size_t)BATCH * HEADS * NQP2 * HD;
  f16* vtb = kb + (size_t)BATCH * HEADS * NKP * HD;
  f16* ob = vtb + (size_t)BATCH * HEADS * NKP * HD;  // [MPAD,768]
  f16* tbl = ob + (size_t)MPAD * DIM;          // [12,17,1088,4,16]

  prep<<<dim3(6540), 256, 0, stream>>>(x, xh, MTOT * DIM, qkv_w, wh,
                                       3 * DIM * DIM, proj_w, pwh, DIM * DIM,
                                       rpb, tbl);
  qkv_gemm<<<dim3(9, 65), 512, 0, stream>>>(xh, wh, q_bias, v_bias, qb, kb,
                                            vtb);
  attn_kernel<<<dim3(BATCH * 5 * HEADS), 512, 0, stream>>>(qb, kb, vtb, tbl,
                                                           ob);
  proj_gemm<<<dim3(3, 65), 512, 0, stream>>>(ob, pwh, proj_b, out);
}